// Round 1
// baseline (383.656 us; speedup 1.0000x reference)
//
#include <hip/hip_runtime.h>

#define N_NODES 10000
#define NE      80000
#define H       32

// ---------------------------------------------------------------------------
// Fused node pipeline: Linear(9,32) -> BN(eval) -> PReLU -> Linear(32,32),
// then fold the downstream linear heads:
//   ns  = h . w_node + b_node
//   p_g = h . (W_c_g @ w_p_g)       (per-node scalar, scatter payload)
//   out[n] = ns + c0 + c1           (c_g = b_c_g . w_p_g + b_p_g)
// h is never materialized to memory.
// ---------------------------------------------------------------------------
__global__ __launch_bounds__(256) void node_kernel(
    const float* __restrict__ x,
    const float* __restrict__ W_in1, const float* __restrict__ b_in1,
    const float* __restrict__ bn_gamma, const float* __restrict__ bn_beta,
    const float* __restrict__ bn_mean, const float* __restrict__ bn_var,
    const float* __restrict__ prelu_a,
    const float* __restrict__ W_in2, const float* __restrict__ b_in2,
    const float* __restrict__ w_node, const float* __restrict__ b_node,
    const float* __restrict__ W_c0, const float* __restrict__ b_c0,
    const float* __restrict__ W_c1, const float* __restrict__ b_c1,
    const float* __restrict__ w_p0, const float* __restrict__ b_p0,
    const float* __restrict__ w_p1, const float* __restrict__ b_p1,
    float* __restrict__ out, float* __restrict__ p0w, float* __restrict__ p1w)
{
    __shared__ float sW1[9 * H];
    __shared__ float sW2[H * H];
    __shared__ float sU0[H], sU1[H], sWn[H];
    __shared__ float sB1[H], sB2[H], sSc[H], sSh[H];
    __shared__ float sC;

    const int t = threadIdx.x;
    for (int i = t; i < 9 * H; i += 256) sW1[i] = W_in1[i];
    for (int i = t; i < H * H; i += 256) sW2[i] = W_in2[i];
    if (t < H) {
        sB1[t] = b_in1[t];
        sB2[t] = b_in2[t];
        float sc = bn_gamma[t] * rsqrtf(bn_var[t] + 1e-5f);
        sSc[t] = sc;
        sSh[t] = bn_beta[t] - bn_mean[t] * sc;
        sWn[t] = w_node[t];
        float u0 = 0.f, u1 = 0.f;
        for (int j = 0; j < H; j++) {
            u0 += W_c0[t * H + j] * w_p0[j];   // u_g[k] = sum_j W_c[k,j] * w_p[j]
            u1 += W_c1[t * H + j] * w_p1[j];
        }
        sU0[t] = u0; sU1[t] = u1;
    }
    if (t == 0) {
        float c0 = b_p0[0], c1 = b_p1[0];
        for (int j = 0; j < H; j++) { c0 += b_c0[j] * w_p0[j]; c1 += b_c1[j] * w_p1[j]; }
        sC = c0 + c1 + b_node[0];
    }
    __syncthreads();

    const float a = prelu_a[0];
    const int n = blockIdx.x * 256 + t;
    if (n >= N_NODES) return;

    float xi[9];
    #pragma unroll
    for (int i = 0; i < 9; i++) xi[i] = x[n * 9 + i];

    float tt[H];
    #pragma unroll
    for (int j = 0; j < H; j++) {
        float s = sB1[j];
        #pragma unroll
        for (int i = 0; i < 9; i++) s += xi[i] * sW1[i * H + j];
        s = s * sSc[j] + sSh[j];           // BN (eval, precomputed scale/shift)
        tt[j] = s >= 0.f ? s : a * s;      // PReLU, shared slope
    }

    float ns = 0.f, p0 = 0.f, p1 = 0.f;
    #pragma unroll
    for (int k = 0; k < H; k++) {
        float h = sB2[k];
        #pragma unroll
        for (int j = 0; j < H; j++) h += tt[j] * sW2[j * H + k];
        ns += h * sWn[k];
        p0 += h * sU0[k];
        p1 += h * sU1[k];
    }
    out[n] = ns + sC;
    p0w[n] = p0;
    p1w[n] = p1;
}

// ---------------------------------------------------------------------------
// Per-node inverse L2 norm: inv[n] = rsqrt(sum(vis[n]^2) + 1e-8).
// One 64-lane wave per node, float4 coalesced loads.
// ---------------------------------------------------------------------------
template <int VD>
__global__ __launch_bounds__(256) void norm_kernel(const float* __restrict__ vis,
                                                   float* __restrict__ inv)
{
    const int wave = (blockIdx.x * 256 + threadIdx.x) >> 6;
    const int lane = threadIdx.x & 63;
    if (wave >= N_NODES) return;
    const float4* v = (const float4*)(vis + (size_t)wave * VD);
    float acc = 0.f;
    #pragma unroll
    for (int it = 0; it < VD / 256; it++) {
        float4 f = v[lane + it * 64];
        acc += f.x * f.x + f.y * f.y + f.z * f.z + f.w * f.w;
    }
    #pragma unroll
    for (int o = 32; o; o >>= 1) acc += __shfl_down(acc, o);
    if (lane == 0) inv[wave] = rsqrtf(acc + 1e-8f);
}

// ---------------------------------------------------------------------------
// Per-edge cosine weight + scalar scatter:
//   w_e = dot(vis[src], vis[dst]) * inv[src] * inv[dst]
//   out[dst] += w_e * p[src]
// One wave per edge; lanes read contiguous float4 (1 KiB/wave/instruction).
// ---------------------------------------------------------------------------
template <int VD>
__global__ __launch_bounds__(256) void edge_kernel(
    const float* __restrict__ vis, const int* __restrict__ ei,
    const float* __restrict__ inv, const float* __restrict__ p,
    float* __restrict__ out)
{
    const int wave = (blockIdx.x * 256 + threadIdx.x) >> 6;
    const int lane = threadIdx.x & 63;
    if (wave >= NE) return;
    const int src = ei[wave];
    const int dst = ei[NE + wave];
    const float4* va = (const float4*)(vis + (size_t)src * VD);
    const float4* vb = (const float4*)(vis + (size_t)dst * VD);
    float acc = 0.f;
    #pragma unroll
    for (int it = 0; it < VD / 256; it++) {
        float4 fa = va[lane + it * 64];
        float4 fb = vb[lane + it * 64];
        acc += fa.x * fb.x + fa.y * fb.y + fa.z * fb.z + fa.w * fb.w;
    }
    #pragma unroll
    for (int o = 32; o; o >>= 1) acc += __shfl_down(acc, o);
    if (lane == 0) {
        float w = acc * inv[src] * inv[dst];
        atomicAdd(&out[dst], w * p[src]);
    }
}

extern "C" void kernel_launch(void* const* d_in, const int* in_sizes, int n_in,
                              void* d_out, int out_size, void* d_ws, size_t ws_size,
                              hipStream_t stream)
{
    const float* x        = (const float*)d_in[0];
    const float* vis0     = (const float*)d_in[1];
    const float* vis1     = (const float*)d_in[2];
    const int*   ei0      = (const int*)d_in[3];
    const int*   ei1      = (const int*)d_in[4];
    const float* W_in1    = (const float*)d_in[5];
    const float* b_in1    = (const float*)d_in[6];
    const float* bn_gamma = (const float*)d_in[7];
    const float* bn_beta  = (const float*)d_in[8];
    const float* bn_mean  = (const float*)d_in[9];
    const float* bn_var   = (const float*)d_in[10];
    const float* prelu_a  = (const float*)d_in[11];
    const float* W_in2    = (const float*)d_in[12];
    const float* b_in2    = (const float*)d_in[13];
    const float* w_node   = (const float*)d_in[14];
    const float* b_node   = (const float*)d_in[15];
    const float* W_c0     = (const float*)d_in[16];
    const float* b_c0     = (const float*)d_in[17];
    const float* W_c1     = (const float*)d_in[18];
    const float* b_c1     = (const float*)d_in[19];
    const float* w_p0     = (const float*)d_in[20];
    const float* b_p0     = (const float*)d_in[21];
    const float* w_p1     = (const float*)d_in[22];
    const float* b_p1     = (const float*)d_in[23];

    float* out  = (float*)d_out;
    float* p0w  = (float*)d_ws;            // [N]
    float* p1w  = p0w + N_NODES;           // [N]
    float* inv0 = p1w + N_NODES;           // [N]
    float* inv1 = inv0 + N_NODES;          // [N]

    node_kernel<<<(N_NODES + 255) / 256, 256, 0, stream>>>(
        x, W_in1, b_in1, bn_gamma, bn_beta, bn_mean, bn_var, prelu_a,
        W_in2, b_in2, w_node, b_node, W_c0, b_c0, W_c1, b_c1,
        w_p0, b_p0, w_p1, b_p1, out, p0w, p1w);

    norm_kernel<2048><<<(N_NODES * 64 + 255) / 256, 256, 0, stream>>>(vis0, inv0);
    norm_kernel<256><<<(N_NODES * 64 + 255) / 256, 256, 0, stream>>>(vis1, inv1);

    edge_kernel<2048><<<(NE * 64 + 255) / 256, 256, 0, stream>>>(vis0, ei0, inv0, p0w, out);
    edge_kernel<256><<<(NE * 64 + 255) / 256, 256, 0, stream>>>(vis1, ei1, inv1, p1w, out);
}

// Round 2
// 292.179 us; speedup vs baseline: 1.3131x; 1.3131x over previous
//
#include <hip/hip_runtime.h>

#define N_NODES 10000
#define NE      80000
#define H       32

// ---------------------------------------------------------------------------
// Fused node pipeline: Linear(9,32) -> BN(eval) -> PReLU -> Linear(32,32),
// then fold downstream linear heads:
//   ns  = h . w_node + b_node
//   p_g = h . (W_c_g @ w_p_g)      (per-node scalar, scatter payload)
//   out[n] = ns + c0 + c1          (c_g = b_c_g . w_p_g + b_p_g)
// ---------------------------------------------------------------------------
__global__ __launch_bounds__(256) void node_kernel(
    const float* __restrict__ x,
    const float* __restrict__ W_in1, const float* __restrict__ b_in1,
    const float* __restrict__ bn_gamma, const float* __restrict__ bn_beta,
    const float* __restrict__ bn_mean, const float* __restrict__ bn_var,
    const float* __restrict__ prelu_a,
    const float* __restrict__ W_in2, const float* __restrict__ b_in2,
    const float* __restrict__ w_node, const float* __restrict__ b_node,
    const float* __restrict__ W_c0, const float* __restrict__ b_c0,
    const float* __restrict__ W_c1, const float* __restrict__ b_c1,
    const float* __restrict__ w_p0, const float* __restrict__ b_p0,
    const float* __restrict__ w_p1, const float* __restrict__ b_p1,
    float* __restrict__ out, float* __restrict__ p0w, float* __restrict__ p1w)
{
    __shared__ float sW1[9 * H];
    __shared__ float sW2[H * H];
    __shared__ float sU0[H], sU1[H], sWn[H];
    __shared__ float sB1[H], sB2[H], sSc[H], sSh[H];
    __shared__ float sC;

    const int t = threadIdx.x;
    for (int i = t; i < 9 * H; i += 256) sW1[i] = W_in1[i];
    for (int i = t; i < H * H; i += 256) sW2[i] = W_in2[i];
    if (t < H) {
        sB1[t] = b_in1[t];
        sB2[t] = b_in2[t];
        float sc = bn_gamma[t] * rsqrtf(bn_var[t] + 1e-5f);
        sSc[t] = sc;
        sSh[t] = bn_beta[t] - bn_mean[t] * sc;
        sWn[t] = w_node[t];
        float u0 = 0.f, u1 = 0.f;
        for (int j = 0; j < H; j++) {
            u0 += W_c0[t * H + j] * w_p0[j];
            u1 += W_c1[t * H + j] * w_p1[j];
        }
        sU0[t] = u0; sU1[t] = u1;
    }
    if (t == 0) {
        float c0 = b_p0[0], c1 = b_p1[0];
        for (int j = 0; j < H; j++) { c0 += b_c0[j] * w_p0[j]; c1 += b_c1[j] * w_p1[j]; }
        sC = c0 + c1 + b_node[0];
    }
    __syncthreads();

    const float a = prelu_a[0];
    const int n = blockIdx.x * 256 + t;
    if (n >= N_NODES) return;

    float xi[9];
    #pragma unroll
    for (int i = 0; i < 9; i++) xi[i] = x[n * 9 + i];

    float tt[H];
    #pragma unroll
    for (int j = 0; j < H; j++) {
        float s = sB1[j];
        #pragma unroll
        for (int i = 0; i < 9; i++) s += xi[i] * sW1[i * H + j];
        s = s * sSc[j] + sSh[j];
        tt[j] = s >= 0.f ? s : a * s;
    }

    float ns = 0.f, p0 = 0.f, p1 = 0.f;
    #pragma unroll
    for (int k = 0; k < H; k++) {
        float h = sB2[k];
        #pragma unroll
        for (int j = 0; j < H; j++) h += tt[j] * sW2[j * H + k];
        ns += h * sWn[k];
        p0 += h * sU0[k];
        p1 += h * sU1[k];
    }
    out[n] = ns + sC;
    p0w[n] = p0;
    p1w[n] = p1;
}

// ---------------------------------------------------------------------------
// bf16 helpers
// ---------------------------------------------------------------------------
__device__ inline unsigned short f2bf_rne(float f) {
    unsigned int u = __float_as_uint(f);
    u += 0x7fffu + ((u >> 16) & 1u);   // round-to-nearest-even
    return (unsigned short)(u >> 16);
}
__device__ inline float bflo(unsigned int u) { return __uint_as_float(u << 16); }
__device__ inline float bfhi(unsigned int u) { return __uint_as_float(u & 0xffff0000u); }

// ---------------------------------------------------------------------------
// Normalize + convert: vn[n] = bf16( vis[n] * rsqrt(sum(vis[n]^2)+1e-8) ).
// One 64-lane wave per node. Row kept in registers between the norm pass
// and the write pass (VD/64 floats per lane).
// ---------------------------------------------------------------------------
template <int VD>
__global__ __launch_bounds__(256) void normconv_kernel(const float* __restrict__ vis,
                                                       unsigned short* __restrict__ vn)
{
    const int node = (blockIdx.x * 256 + threadIdx.x) >> 6;
    const int lane = threadIdx.x & 63;
    if (node >= N_NODES) return;
    const float4* v = (const float4*)(vis + (size_t)node * VD);
    float4 f[VD / 256];
    float acc = 0.f;
    #pragma unroll
    for (int it = 0; it < VD / 256; it++) {
        f[it] = v[it * 64 + lane];
        acc += f[it].x * f[it].x + f[it].y * f[it].y + f[it].z * f[it].z + f[it].w * f[it].w;
    }
    #pragma unroll
    for (int o = 32; o; o >>= 1) acc += __shfl_xor(acc, o);   // butterfly: all lanes get sum
    const float inv = rsqrtf(acc + 1e-8f);

    ushort4* o4 = (ushort4*)(vn + (size_t)node * VD);
    #pragma unroll
    for (int it = 0; it < VD / 256; it++) {
        ushort4 r;
        r.x = f2bf_rne(f[it].x * inv);
        r.y = f2bf_rne(f[it].y * inv);
        r.z = f2bf_rne(f[it].z * inv);
        r.w = f2bf_rne(f[it].w * inv);
        o4[it * 64 + lane] = r;
    }
}

// ---------------------------------------------------------------------------
// Per-edge cosine from pre-normalized bf16 rows + scalar scatter:
//   out[dst] += dot(vn[src], vn[dst]) * p[src]
// One wave per edge; VD=2048: 4 iters of uint4 (8 bf16) per lane.
// ---------------------------------------------------------------------------
__device__ inline float dot8_bf16(uint4 a, uint4 b) {
    float s;
    s  = bflo(a.x) * bflo(b.x) + bfhi(a.x) * bfhi(b.x);
    s += bflo(a.y) * bflo(b.y) + bfhi(a.y) * bfhi(b.y);
    s += bflo(a.z) * bflo(b.z) + bfhi(a.z) * bfhi(b.z);
    s += bflo(a.w) * bflo(b.w) + bfhi(a.w) * bfhi(b.w);
    return s;
}

template <int VD>
__global__ __launch_bounds__(256) void edge_bf16_kernel(
    const unsigned short* __restrict__ vn, const int* __restrict__ ei,
    const float* __restrict__ p, float* __restrict__ out)
{
    const int e    = (blockIdx.x * 256 + threadIdx.x) >> 6;
    const int lane = threadIdx.x & 63;
    if (e >= NE) return;
    const int src = ei[e];
    const int dst = ei[NE + e];
    float acc = 0.f;
    if constexpr (VD >= 512) {
        const uint4* pa = (const uint4*)(vn + (size_t)src * VD);
        const uint4* pb = (const uint4*)(vn + (size_t)dst * VD);
        #pragma unroll
        for (int it = 0; it < VD / 512; it++) {
            uint4 a = pa[it * 64 + lane];
            uint4 b = pb[it * 64 + lane];
            acc += dot8_bf16(a, b);
        }
    } else {
        // VD=256: uint2 (4 bf16) per lane, single iteration
        const uint2* pa = (const uint2*)(vn + (size_t)src * VD);
        const uint2* pb = (const uint2*)(vn + (size_t)dst * VD);
        uint2 a = pa[lane];
        uint2 b = pb[lane];
        acc  = bflo(a.x) * bflo(b.x) + bfhi(a.x) * bfhi(b.x);
        acc += bflo(a.y) * bflo(b.y) + bfhi(a.y) * bfhi(b.y);
    }
    #pragma unroll
    for (int o = 32; o; o >>= 1) acc += __shfl_down(acc, o);
    if (lane == 0) atomicAdd(&out[dst], acc * p[src]);
}

// ---------------------------------------------------------------------------
// fp32 fallback (used only if ws_size can't hold the bf16 rows)
// ---------------------------------------------------------------------------
template <int VD>
__global__ __launch_bounds__(256) void norm_kernel(const float* __restrict__ vis,
                                                   float* __restrict__ inv)
{
    const int wave = (blockIdx.x * 256 + threadIdx.x) >> 6;
    const int lane = threadIdx.x & 63;
    if (wave >= N_NODES) return;
    const float4* v = (const float4*)(vis + (size_t)wave * VD);
    float acc = 0.f;
    #pragma unroll
    for (int it = 0; it < VD / 256; it++) {
        float4 f = v[lane + it * 64];
        acc += f.x * f.x + f.y * f.y + f.z * f.z + f.w * f.w;
    }
    #pragma unroll
    for (int o = 32; o; o >>= 1) acc += __shfl_down(acc, o);
    if (lane == 0) inv[wave] = rsqrtf(acc + 1e-8f);
}

template <int VD>
__global__ __launch_bounds__(256) void edge_kernel(
    const float* __restrict__ vis, const int* __restrict__ ei,
    const float* __restrict__ inv, const float* __restrict__ p,
    float* __restrict__ out)
{
    const int wave = (blockIdx.x * 256 + threadIdx.x) >> 6;
    const int lane = threadIdx.x & 63;
    if (wave >= NE) return;
    const int src = ei[wave];
    const int dst = ei[NE + wave];
    const float4* va = (const float4*)(vis + (size_t)src * VD);
    const float4* vb = (const float4*)(vis + (size_t)dst * VD);
    float acc = 0.f;
    #pragma unroll
    for (int it = 0; it < VD / 256; it++) {
        float4 fa = va[lane + it * 64];
        float4 fb = vb[lane + it * 64];
        acc += fa.x * fb.x + fa.y * fb.y + fa.z * fb.z + fa.w * fb.w;
    }
    #pragma unroll
    for (int o = 32; o; o >>= 1) acc += __shfl_down(acc, o);
    if (lane == 0) {
        float w = acc * inv[src] * inv[dst];
        atomicAdd(&out[dst], w * p[src]);
    }
}

extern "C" void kernel_launch(void* const* d_in, const int* in_sizes, int n_in,
                              void* d_out, int out_size, void* d_ws, size_t ws_size,
                              hipStream_t stream)
{
    const float* x        = (const float*)d_in[0];
    const float* vis0     = (const float*)d_in[1];
    const float* vis1     = (const float*)d_in[2];
    const int*   ei0      = (const int*)d_in[3];
    const int*   ei1      = (const int*)d_in[4];
    const float* W_in1    = (const float*)d_in[5];
    const float* b_in1    = (const float*)d_in[6];
    const float* bn_gamma = (const float*)d_in[7];
    const float* bn_beta  = (const float*)d_in[8];
    const float* bn_mean  = (const float*)d_in[9];
    const float* bn_var   = (const float*)d_in[10];
    const float* prelu_a  = (const float*)d_in[11];
    const float* W_in2    = (const float*)d_in[12];
    const float* b_in2    = (const float*)d_in[13];
    const float* w_node   = (const float*)d_in[14];
    const float* b_node   = (const float*)d_in[15];
    const float* W_c0     = (const float*)d_in[16];
    const float* b_c0     = (const float*)d_in[17];
    const float* W_c1     = (const float*)d_in[18];
    const float* b_c1     = (const float*)d_in[19];
    const float* w_p0     = (const float*)d_in[20];
    const float* b_p0     = (const float*)d_in[21];
    const float* w_p1     = (const float*)d_in[22];
    const float* b_p1     = (const float*)d_in[23];

    float* out = (float*)d_out;

    // workspace layout
    char* ws = (char*)d_ws;
    float* p0w  = (float*)ws;                           ws += N_NODES * 4;
    float* p1w  = (float*)ws;                           ws += N_NODES * 4;
    float* inv0 = (float*)ws;                           ws += N_NODES * 4;
    float* inv1 = (float*)ws;                           ws += N_NODES * 4;
    unsigned short* vn0 = (unsigned short*)ws;          ws += (size_t)N_NODES * 2048 * 2;
    unsigned short* vn1 = (unsigned short*)ws;          ws += (size_t)N_NODES * 256 * 2;
    const size_t need = (size_t)(ws - (char*)d_ws);

    node_kernel<<<(N_NODES + 255) / 256, 256, 0, stream>>>(
        x, W_in1, b_in1, bn_gamma, bn_beta, bn_mean, bn_var, prelu_a,
        W_in2, b_in2, w_node, b_node, W_c0, b_c0, W_c1, b_c1,
        w_p0, b_p0, w_p1, b_p1, out, p0w, p1w);

    if (ws_size >= need) {
        normconv_kernel<2048><<<(N_NODES * 64 + 255) / 256, 256, 0, stream>>>(vis0, vn0);
        normconv_kernel<256><<<(N_NODES * 64 + 255) / 256, 256, 0, stream>>>(vis1, vn1);
        edge_bf16_kernel<2048><<<(NE * 64 + 255) / 256, 256, 0, stream>>>(vn0, ei0, p0w, out);
        edge_bf16_kernel<256><<<(NE * 64 + 255) / 256, 256, 0, stream>>>(vn1, ei1, p1w, out);
    } else {
        norm_kernel<2048><<<(N_NODES * 64 + 255) / 256, 256, 0, stream>>>(vis0, inv0);
        norm_kernel<256><<<(N_NODES * 64 + 255) / 256, 256, 0, stream>>>(vis1, inv1);
        edge_kernel<2048><<<(NE * 64 + 255) / 256, 256, 0, stream>>>(vis0, ei0, inv0, p0w, out);
        edge_kernel<256><<<(NE * 64 + 255) / 256, 256, 0, stream>>>(vis1, ei1, inv1, p1w, out);
    }
}